// Round 8
// baseline (310.065 us; speedup 1.0000x reference)
//
#include <hip/hip_runtime.h>

#define HORIZON 2048
#define B_TOTAL 4096
#define T_OUT 2047

// Hardware transcendentals (v_exp_f32 = 2^x, v_rcp_f32 = 1/x, ~1 ulp)
__device__ __forceinline__ float hw_exp2(float x) {
    float r;
    asm("v_exp_f32 %0, %1" : "=v"(r) : "v"(x));
    return r;
}
__device__ __forceinline__ float hw_rcp(float x) {
    float r;
    asm("v_rcp_f32 %0, %1" : "=v"(r) : "v"(x));
    return r;
}

// Magic-constant reciprocal + 2 Newton iterations.
// For s in [1, 2^60+1]: seed rel-err ~5% -> 2.5e-3 -> ~6e-6. 5 VALU ops,
// all full-rate, vs v_rcp_f32's 16-cy trans-pipe issue slot.
__device__ __forceinline__ float fast_rcp(float s) {
    float r = __int_as_float(0x7EF311C3 - __float_as_int(s));
    r = r * fmaf(-s, r, 2.f);
    r = r * fmaf(-s, r, 2.f);
    return r;
}

// DPP-mapped move (VALU pipe); fuses into v_add_f32_dpp
template<int CTRL>
__device__ __forceinline__ float dpp_mov(float v) {
    return __int_as_float(__builtin_amdgcn_update_dpp(
        0, __float_as_int(v), CTRL, 0xF, 0xF, true));
}

// Sum over each 16-lane DPP row; result uniform across the 16 lanes.
__device__ __forceinline__ float rowsum16(float v) {
    v += dpp_mov<0xB1>(v);   // quad_perm xor1
    v += dpp_mov<0x4E>(v);   // quad_perm xor2
    v += dpp_mov<0x124>(v);  // row_ror:4
    v += dpp_mov<0x128>(v);  // row_ror:8
    return v;
}

#define K1  2.8853900817779268f    // 2*log2(e): tanh(a) = 1 - 2/(2^(K1*a)+1)
#define CS -24.04491734814939f     // -log2(e)/0.06: sigmoid(z/tau)=1/(1+2^(CS*z))
#define ECLAMP 1.152921504606847e18f   // 2^60: keeps fast_rcp input finite

__global__ __launch_bounds__(64) void thermostat_scan4(
    const float* __restrict__ d,
    const float* __restrict__ W1,
    const float* __restrict__ b1,
    const float* __restrict__ W2,
    const float* __restrict__ b2,
    float* __restrict__ xs,
    float* __restrict__ us)
{
    const int lane = threadIdx.x;        // 0..63
    const int sub  = lane >> 4;          // batch row within wave (0..3)
    const int pos  = lane & 15;          // lane position within 16-row
    const int grow = blockIdx.x * 4 + sub;

    const float* drow = d + (size_t)grow * HORIZON;
    const float4* dv  = (const float4*)drow;

    // Lane owns hidden units j = pos + 16k, k=0..3. Constants folded.
    float w10c[4], w11c[4], b1c[4], w20m[4], w21m[4];
    float s20p = 0.f, s21p = 0.f;
#pragma unroll
    for (int k = 0; k < 4; ++k) {
        int j = pos + 16 * k;
        w10c[k] = W1[j] * K1;
        w11c[k] = W1[64 + j] * K1;
        b1c[k]  = b1[j] * K1;
        float a0 = W2[2 * j], a1 = W2[2 * j + 1];
        w20m[k] = -2.f * a0;
        w21m[k] = -2.f * a1;
        s20p += a0;
        s21p += a1;
    }
    // Column sums of W2 (loop-invariant): z = zb + sum_j(-2 r_j w_j)
    const float zb0  = rowsum16(s20p) + b2[0];
    const float zb1c = (rowsum16(s21p) + b2[1]) * CS;

    float* xs_p = xs + (size_t)grow * T_OUT + pos;
    float* us_p = us + (size_t)grow * T_OUT + pos;

    float4 c0 = dv[0], c1 = dv[1], c2 = dv[2], c3 = dv[3];
    float4 n0 = dv[4], n1 = dv[5], n2 = dv[6], n3 = dv[7];

    float x = c0.x;                 // x0
    float keep_x = x;
    float keep_u = -zb0;            // (+zb0 at store) = 0

    auto step = [&](float dt, int slot) {
        // layer 1 + tanh: r_k = 1/(exp2(K1*a_k)+1)  (4 exps on trans pipe)
        float e0 = hw_exp2(fmaf(x, w10c[0], fmaf(dt, w11c[0], b1c[0])));
        float e1 = hw_exp2(fmaf(x, w10c[1], fmaf(dt, w11c[1], b1c[1])));
        float e2 = hw_exp2(fmaf(x, w10c[2], fmaf(dt, w11c[2], b1c[2])));
        float e3 = hw_exp2(fmaf(x, w10c[3], fmaf(dt, w11c[3], b1c[3])));
        // s = min(e+1, 2^60) keeps fast_rcp's magic-seed finite (e can be inf)
        float r0 = fast_rcp(fminf(e0 + 1.f, ECLAMP));
        float r1 = fast_rcp(fminf(e1 + 1.f, ECLAMP));
        float r2 = fast_rcp(fminf(e2 + 1.f, ECLAMP));
        float r3 = fast_rcp(fminf(e3 + 1.f, ECLAMP));
        // column partials (z = zb + sum -2 r w)
        float q1 = fmaf(r1, w21m[1], r0 * w21m[0])
                 + fmaf(r3, w21m[3], r2 * w21m[2]);
        float z1 = rowsum16(q1);                  // critical path
        float q0 = fmaf(r1, w20m[1], r0 * w20m[0])
                 + fmaf(r3, w20m[3], r2 * w20m[2]);
        float z0 = rowsum16(q0);                  // off critical path
        // u_bin = sigmoid(z1full/tau) = 1/(1+2^as); skip trans when all 4
        // rows saturated (|as|>=30 -> ub error < 1e-9: exact in fp32)
        float as = fmaf(z1, CS, zb1c);
        float ub;
        if (__any(fabsf(as) < 30.f)) {
            ub = hw_rcp(1.f + hw_exp2(as));
        } else {
            ub = as < 0.f ? 1.f : 0.f;
        }
        // x_new = 0.99x + 0.4 ub - dt
        x = fmaf(0.99f, x, fmaf(0.4f, ub, -dt));
        // stash outputs in the owning lane
        bool kk = (pos == slot);
        keep_x = kk ? x : keep_x;
        keep_u = kk ? z0 : keep_u;
    };

    // ---- chunk 0: steps t=1..15 (slot 0 holds x0 / 0) ----
    {
        float dt16[16] = {c0.x, c0.y, c0.z, c0.w, c1.x, c1.y, c1.z, c1.w,
                          c2.x, c2.y, c2.z, c2.w, c3.x, c3.y, c3.z, c3.w};
#pragma unroll
        for (int s = 1; s < 16; ++s) step(dt16[s], s);
        xs_p[0] = keep_x;
        us_p[0] = keep_u + zb0;
    }

    // ---- chunks 1..126 (16 steps each), prefetch chunk c+1 ----
    for (int c = 1; c < 127; ++c) {
        c0 = n0; c1 = n1; c2 = n2; c3 = n3;
        n0 = dv[4 * c + 4]; n1 = dv[4 * c + 5];
        n2 = dv[4 * c + 6]; n3 = dv[4 * c + 7];
        float dt16[16] = {c0.x, c0.y, c0.z, c0.w, c1.x, c1.y, c1.z, c1.w,
                          c2.x, c2.y, c2.z, c2.w, c3.x, c3.y, c3.z, c3.w};
#pragma unroll
        for (int s = 0; s < 16; ++s) step(dt16[s], s);
        xs_p[c * 16] = keep_x;
        us_p[c * 16] = keep_u + zb0;
    }

    // ---- chunk 127: steps t=2032..2046 (15 steps, slots 0..14) ----
    {
        float dt16[16] = {n0.x, n0.y, n0.z, n0.w, n1.x, n1.y, n1.z, n1.w,
                          n2.x, n2.y, n2.z, n2.w, n3.x, n3.y, n3.z, n3.w};
#pragma unroll
        for (int s = 0; s < 15; ++s) step(dt16[s], s);
        if (pos < 15) {
            xs_p[127 * 16] = keep_x;
            us_p[127 * 16] = keep_u + zb0;
        }
    }
}

extern "C" void kernel_launch(void* const* d_in, const int* in_sizes, int n_in,
                              void* d_out, int out_size, void* d_ws, size_t ws_size,
                              hipStream_t stream) {
    const float* d  = (const float*)d_in[0];
    const float* W1 = (const float*)d_in[1];
    const float* b1 = (const float*)d_in[2];
    const float* W2 = (const float*)d_in[3];
    const float* b2 = (const float*)d_in[4];
    float* xs = (float*)d_out;
    float* us = xs + (size_t)B_TOTAL * T_OUT;

    dim3 grid(B_TOTAL / 4);   // 1024 waves, 4 batch rows per wave, 1 wave/SIMD
    thermostat_scan4<<<grid, 64, 0, stream>>>(d, W1, b1, W2, b2, xs, us);
}

// Round 9
// 221.939 us; speedup vs baseline: 1.3971x; 1.3971x over previous
//
#include <hip/hip_runtime.h>

#define HORIZON 2048
#define B_TOTAL 4096
#define T_OUT 2047

// Hardware transcendentals (v_exp_f32 = 2^x, v_rcp_f32 = 1/x, ~1 ulp)
__device__ __forceinline__ float hw_exp2(float x) {
    float r;
    asm("v_exp_f32 %0, %1" : "=v"(r) : "v"(x));
    return r;
}
__device__ __forceinline__ float hw_rcp(float x) {
    float r;
    asm("v_rcp_f32 %0, %1" : "=v"(r) : "v"(x));
    return r;
}

// DPP-mapped move (VALU pipe)
template<int CTRL>
__device__ __forceinline__ float dpp_mov(float v) {
    return __int_as_float(__builtin_amdgcn_update_dpp(
        0, __float_as_int(v), CTRL, 0xF, 0xF, true));
}

// Sum over each 16-lane DPP row; result uniform across all 16 lanes of the row.
// xor1 (quad_perm[1,0,3,2]=0xB1), xor2 (quad_perm[2,3,0,1]=0x4E),
// then rotate-reduce ror:4, ror:8 (valid because values are quad-uniform).
__device__ __forceinline__ float rowsum16(float v) {
    v += dpp_mov<0xB1>(v);
    v += dpp_mov<0x4E>(v);
    v += dpp_mov<0x124>(v);  // row_ror:4
    v += dpp_mov<0x128>(v);  // row_ror:8
    return v;
}

#define K1  2.8853900817779268f    // 2*log2(e): tanh(a) = 1 - 2/(2^(K1*a)+1)
#define CS -24.04491734814939f     // -log2(e)/0.06: sigmoid(z/tau) = 1/(1+2^(CS*z))

__global__ __launch_bounds__(64) void thermostat_scan4(
    const float* __restrict__ d,
    const float* __restrict__ W1,
    const float* __restrict__ b1,
    const float* __restrict__ W2,
    const float* __restrict__ b2,
    float* __restrict__ xs,
    float* __restrict__ us)
{
    const int lane = threadIdx.x;        // 0..63
    const int sub  = lane >> 4;          // batch row within wave (0..3)
    const int pos  = lane & 15;          // lane position within 16-row
    const int grow = blockIdx.x * 4 + sub;

    const float* drow = d + (size_t)grow * HORIZON;
    const float4* dv  = (const float4*)drow;

    // Each lane owns hidden units j = pos + 16k, k=0..3. Constants folded.
    float w10c[4], w11c[4], b1c[4], w20m[4], w21m[4];
    float s20p = 0.f, s21p = 0.f;
#pragma unroll
    for (int k = 0; k < 4; ++k) {
        int j = pos + 16 * k;
        w10c[k] = W1[j] * K1;
        w11c[k] = W1[64 + j] * K1;
        b1c[k]  = b1[j] * K1;
        float a0 = W2[2 * j], a1 = W2[2 * j + 1];
        w20m[k] = -2.f * a0;
        w21m[k] = -2.f * a1;
        s20p += a0;
        s21p += a1;
    }
    // Column sums of W2 (identical for every row): z = zb + sum_j(-2 r_j w_j)
    const float zb0  = rowsum16(s20p) + b2[0];
    const float zb1c = (rowsum16(s21p) + b2[1]) * CS;   // folded into sigmoid arg

    float* xs_p = xs + (size_t)grow * T_OUT + pos;
    float* us_p = us + (size_t)grow * T_OUT + pos;

    // chunk 0 data (t=0..15); element 0 is x0
    float4 c0 = dv[0], c1 = dv[1], c2 = dv[2], c3 = dv[3];
    // prefetch chunk 1
    float4 n0 = dv[4], n1 = dv[5], n2 = dv[6], n3 = dv[7];

    float x = c0.x;                 // x0 (uniform within 16-row)
    float keep_x = x;               // pos-0 slot of chunk 0
    float keep_u = -zb0;            // (+zb0 at store) = 0

    auto step = [&](float dt, int slot) {
        // layer 1 + tanh for 4 units: r_k = 1/(exp2(K1*a_k)+1), h = 1-2r
        float e0 = hw_exp2(fmaf(x, w10c[0], fmaf(dt, w11c[0], b1c[0])));
        float e1 = hw_exp2(fmaf(x, w10c[1], fmaf(dt, w11c[1], b1c[1])));
        float e2 = hw_exp2(fmaf(x, w10c[2], fmaf(dt, w11c[2], b1c[2])));
        float e3 = hw_exp2(fmaf(x, w10c[3], fmaf(dt, w11c[3], b1c[3])));
        float r0 = hw_rcp(e0 + 1.f);
        float r1 = hw_rcp(e1 + 1.f);
        float r2 = hw_rcp(e2 + 1.f);
        float r3 = hw_rcp(e3 + 1.f);
        // column partials, tree-combined (constant part hoisted into zb*)
        float q1a = fmaf(r1, w21m[1], r0 * w21m[0]);
        float q1b = fmaf(r3, w21m[3], r2 * w21m[2]);
        float z1  = rowsum16(q1a + q1b);        // critical path
        float q0a = fmaf(r1, w20m[1], r0 * w20m[0]);
        float q0b = fmaf(r3, w20m[3], r2 * w20m[2]);
        float z0  = rowsum16(q0a + q0b);        // off critical path
        // u_bin = 1/(1+2^(CS*z1full)); biases pre-folded in zb1c
        float ub = hw_rcp(1.f + hw_exp2(fmaf(z1, CS, zb1c)));
        // x_new = 0.99x + 0.4 ub - dt   (uniform within 16-row)
        x = fmaf(0.99f, x, fmaf(0.4f, ub, -dt));
        // stash outputs in the owning lane
        bool k = (pos == slot);
        keep_x = k ? x : keep_x;
        keep_u = k ? z0 : keep_u;
    };

    // ---- chunk 0: steps t=1..15 (slot 0 holds x0 / 0) ----
    {
        float dt16[16] = {c0.x, c0.y, c0.z, c0.w, c1.x, c1.y, c1.z, c1.w,
                          c2.x, c2.y, c2.z, c2.w, c3.x, c3.y, c3.z, c3.w};
#pragma unroll
        for (int s = 1; s < 16; ++s) step(dt16[s], s);
        xs_p[0] = keep_x;
        us_p[0] = keep_u + zb0;
    }

    // ---- chunks 1..126 (16 steps each), prefetch chunk c+1 ----
    for (int c = 1; c < 127; ++c) {
        c0 = n0; c1 = n1; c2 = n2; c3 = n3;
        n0 = dv[4 * c + 4]; n1 = dv[4 * c + 5];
        n2 = dv[4 * c + 6]; n3 = dv[4 * c + 7];
        float dt16[16] = {c0.x, c0.y, c0.z, c0.w, c1.x, c1.y, c1.z, c1.w,
                          c2.x, c2.y, c2.z, c2.w, c3.x, c3.y, c3.z, c3.w};
#pragma unroll
        for (int s = 0; s < 16; ++s) step(dt16[s], s);
        xs_p[c * 16] = keep_x;
        us_p[c * 16] = keep_u + zb0;
    }

    // ---- chunk 127: steps t=2032..2046 (15 steps, slots 0..14) ----
    {
        float dt16[16] = {n0.x, n0.y, n0.z, n0.w, n1.x, n1.y, n1.z, n1.w,
                          n2.x, n2.y, n2.z, n2.w, n3.x, n3.y, n3.z, n3.w};
#pragma unroll
        for (int s = 0; s < 15; ++s) step(dt16[s], s);
        if (pos < 15) {
            xs_p[127 * 16] = keep_x;
            us_p[127 * 16] = keep_u + zb0;
        }
    }
}

extern "C" void kernel_launch(void* const* d_in, const int* in_sizes, int n_in,
                              void* d_out, int out_size, void* d_ws, size_t ws_size,
                              hipStream_t stream) {
    const float* d  = (const float*)d_in[0];
    const float* W1 = (const float*)d_in[1];
    const float* b1 = (const float*)d_in[2];
    const float* W2 = (const float*)d_in[3];
    const float* b2 = (const float*)d_in[4];
    float* xs = (float*)d_out;
    float* us = xs + (size_t)B_TOTAL * T_OUT;

    dim3 grid(B_TOTAL / 4);   // 1024 blocks x 1 wave, 4 batch rows per wave
    thermostat_scan4<<<grid, 64, 0, stream>>>(d, W1, b1, W2, b2, xs, us);
}